// Round 1
// 53.823 us; speedup vs baseline: 1.1732x; 1.1732x over previous
//
#include <hip/hip_runtime.h>

typedef short s4v __attribute__((ext_vector_type(4)));
typedef short s8v __attribute__((ext_vector_type(8)));
typedef float f4v __attribute__((ext_vector_type(4)));
typedef float f16v __attribute__((ext_vector_type(16)));

#define ND 4096
#define NMASK 4095

__device__ __forceinline__ unsigned short f2bf(float f) {
  __bf16 h = (__bf16)f;
  return __builtin_bit_cast(unsigned short, h);
}

// BM=64, BN=128, BK=64. 256 threads = 4 waves: wn = wv&1 (64-col band),
// kb = wv>>1 (K-half). Each wave computes the full 64 rows x its 64 cols
// over half of K (2x2 fragments of 32x32x16), cross-wave reduced in LDS.
// wl is a 4-fold sliding window: wl[4s+t] = bf16(W[(s+t)&4095]) so any
// 8-element circulant window starting at s is two aligned ds_read_b64 at
// bytes 8s and 8((s+4)&4095); consecutive lanes step banks by 2 -> each
// 16-lane phase tiles all 32 banks (conflict-free).
__global__ __launch_bounds__(256, 3)
void circ_mm(const float* __restrict__ X, const float* __restrict__ W,
             const float* __restrict__ bias, float* __restrict__ C) {
  extern __shared__ unsigned short smem[];
  unsigned short* __restrict__ wl = smem;            // 16384 bf16 = 32 KB
  unsigned short* __restrict__ al = smem + 4 * ND;   // dbuf 2 x [64][64] bf16 = 16 KB

  const int tid = threadIdx.x;
  const int bid = blockIdx.x;
  // XCD-aware mapping: XCD x serves m-panels {x, x+8}; 32 n-tiles share the
  // 1 MB X panel in that XCD's L2.
  const int x = bid & 7;
  const int i = bid >> 3;
  const int m0 = (x + ((i >> 5) << 3)) << 6;   // 0..960
  const int n0 = (i & 31) << 7;                // 0..3968

  // ---- build sliding-window W copies: wl[e] = bf16(W[((e>>2)+(e&3)) & 4095]) ----
  for (int e2 = tid; e2 < 8192; e2 += 256) {
    const int m = e2 << 1;
    const int i0 = ((m >> 2) + (m & 3)) & NMASK;
    const int i1 = (((m + 1) >> 2) + ((m + 1) & 3)) & NMASK;
    *(unsigned int*)(&wl[m]) =
        (unsigned int)f2bf(W[i0]) | ((unsigned int)f2bf(W[i1]) << 16);
  }

  // ---- A staging geometry: thread covers (srow, 16 consecutive k) ----
  const int srow = tid >> 2;        // 0..63
  const int skq = tid & 3;
  const float* gA = X + (m0 + srow) * ND + skq * 16;
  const int sswz = (srow & 7) << 3;
  const int woff0 = srow * 64 + ((skq * 16 + 0) ^ sswz);
  const int woff1 = srow * 64 + ((skq * 16 + 8) ^ sswz);

  // ---- fragment geometry ----
  const int lane = tid & 63;
  const int lc = lane & 31;
  const int lh8 = (lane >> 5) << 3;
  const int wv = tid >> 6;
  const int wn = wv & 1;            // 64-col band within block
  const int kb = wv >> 1;           // K-half (k16 pair)

  int aoff[2][2];                   // [mf][kq]
  #pragma unroll
  for (int mf = 0; mf < 2; ++mf) {
    const int row = mf * 32 + lc;
    const int rswz = (row & 7) << 3;
    #pragma unroll
    for (int kq = 0; kq < 2; ++kq)
      aoff[mf][kq] = row * 64 + ((kb * 32 + kq * 16 + lh8) ^ rswz);
  }

  int c08[2];                       // (-col)&4095 + lh8, per n-fragment
  #pragma unroll
  for (int nf = 0; nf < 2; ++nf) {
    const int col = n0 + wn * 64 + nf * 32 + lc;
    c08[nf] = ((-col) & NMASK) + lh8;
  }

  f16v acc[2][2];
  #pragma unroll
  for (int mf = 0; mf < 2; ++mf)
    #pragma unroll
    for (int nf = 0; nf < 2; ++nf)
      #pragma unroll
      for (int e = 0; e < 16; ++e) acc[mf][nf][e] = 0.f;

  // ---- prologue: stage A tile 0 ----
  {
    f4v g0 = *(const f4v*)(gA + 0);
    f4v g1 = *(const f4v*)(gA + 4);
    f4v g2 = *(const f4v*)(gA + 8);
    f4v g3 = *(const f4v*)(gA + 12);
    s8v u0, u1;
    #pragma unroll
    for (int j = 0; j < 4; ++j) {
      u0[j] = (short)f2bf(g0[j]); u0[4 + j] = (short)f2bf(g1[j]);
      u1[j] = (short)f2bf(g2[j]); u1[4 + j] = (short)f2bf(g3[j]);
    }
    *(s8v*)(&al[woff0]) = u0;
    *(s8v*)(&al[woff1]) = u1;
  }
  __syncthreads();

  // ---- main K loop: 64 tiles of BK=64, one barrier per tile (T14 split) ----
  #pragma unroll 2
  for (int t = 0; t < 64; ++t) {
    const unsigned short* ab = al + (t & 1) * 4096;

    f4v g0, g1, g2, g3;
    if (t < 63) {                    // issue next-tile global loads first
      const float* gp = gA + (t + 1) * 64;
      g0 = *(const f4v*)(gp + 0);
      g1 = *(const f4v*)(gp + 4);
      g2 = *(const f4v*)(gp + 8);
      g3 = *(const f4v*)(gp + 12);
    }

    const int tk = t * 64 + kb * 32;
    #pragma unroll
    for (int kq = 0; kq < 2; ++kq) {
      const s8v a0 = *(const s8v*)(&ab[aoff[0][kq]]);
      const s8v a1 = *(const s8v*)(&ab[aoff[1][kq]]);
      #pragma unroll
      for (int nf = 0; nf < 2; ++nf) {
        const int s = (tk + kq * 16 + c08[nf]) & NMASK;
        const int o0 = s << 2;
        const int o1 = (o0 + 16) & 16383;
        const s4v blo = *(const s4v*)(&wl[o0]);
        const s4v bhi = *(const s4v*)(&wl[o1]);
        const s8v b = __builtin_shufflevector(blo, bhi, 0, 1, 2, 3, 4, 5, 6, 7);
        acc[0][nf] = __builtin_amdgcn_mfma_f32_32x32x16_bf16(a0, b, acc[0][nf], 0, 0, 0);
        acc[1][nf] = __builtin_amdgcn_mfma_f32_32x32x16_bf16(a1, b, acc[1][nf], 0, 0, 0);
      }
    }

    if (t < 63) {                    // convert + LDS-write after compute
      unsigned short* aw = al + ((t + 1) & 1) * 4096;
      s8v u0, u1;
      #pragma unroll
      for (int j = 0; j < 4; ++j) {
        u0[j] = (short)f2bf(g0[j]); u0[4 + j] = (short)f2bf(g1[j]);
        u1[j] = (short)f2bf(g2[j]); u1[4 + j] = (short)f2bf(g3[j]);
      }
      *(s8v*)(&aw[woff0]) = u0;
      *(s8v*)(&aw[woff1]) = u1;
    }
    __syncthreads();
  }

  // ---- epilogue: K-half reduction in LDS, then bias + store ----
  // C/D map: col=lane&31, row=(reg&3)+8*(reg>>2)+4*(lane>>5)
  const int lh4 = (lane >> 5) << 2;
  float* red = (float*)smem;        // [2][64][64] f32 = 32 KB (overlays wl)

  if (kb == 1) {
    #pragma unroll
    for (int mf = 0; mf < 2; ++mf)
      #pragma unroll
      for (int nf = 0; nf < 2; ++nf)
        #pragma unroll
        for (int g = 0; g < 4; ++g)
          #pragma unroll
          for (int e = 0; e < 4; ++e)
            red[(wn << 12) + (mf * 32 + g * 8 + lh4 + e) * 64 + nf * 32 + lc] =
                acc[mf][nf][g * 4 + e];
  }
  __syncthreads();
  if (kb == 0) {
    #pragma unroll
    for (int mf = 0; mf < 2; ++mf)
      #pragma unroll
      for (int nf = 0; nf < 2; ++nf) {
        const int col = n0 + wn * 64 + nf * 32 + lc;
        const float bv = bias[col];
        #pragma unroll
        for (int g = 0; g < 4; ++g) {
          const int row = m0 + mf * 32 + g * 8 + lh4;
          #pragma unroll
          for (int e = 0; e < 4; ++e)
            C[(row + e) * ND + col] =
                acc[mf][nf][g * 4 + e] +
                red[(wn << 12) + (mf * 32 + g * 8 + lh4 + e) * 64 + nf * 32 + lc] + bv;
        }
      }
  }
}

extern "C" void kernel_launch(void* const* d_in, const int* in_sizes, int n_in,
                              void* d_out, int out_size, void* d_ws, size_t ws_size,
                              hipStream_t stream) {
  (void)hipFuncSetAttribute((const void*)circ_mm,
                            hipFuncAttributeMaxDynamicSharedMemorySize, 49152);
  const float* X    = (const float*)d_in[0];
  const float* W    = (const float*)d_in[1];
  const float* bias = (const float*)d_in[2];
  circ_mm<<<dim3(512), dim3(256), 49152, stream>>>(X, W, bias, (float*)d_out);
}

// Round 2
// 52.557 us; speedup vs baseline: 1.2014x; 1.0241x over previous
//
#include <hip/hip_runtime.h>

typedef short s4v __attribute__((ext_vector_type(4)));
typedef short s8v __attribute__((ext_vector_type(8)));
typedef float f4v __attribute__((ext_vector_type(4)));
typedef float f16v __attribute__((ext_vector_type(16)));

#define ND 4096
#define NMASK 4095

__device__ __forceinline__ unsigned short f2bf(float f) {
  __bf16 h = (__bf16)f;
  return __builtin_bit_cast(unsigned short, h);
}

// BM=64, BN=128, BK=64. 512 threads = 8 waves: wn = wv&1 (64-col band),
// kb = wv>>2? no: kb = wv>>1 (K-quarter, 16 k per tile per wave).
// Each wave computes the full 64 rows x its 64 cols (2x2 fragments of
// 32x32x16) over a quarter of K; 4-way cross-wave LDS reduction at the end.
// wl is an 8-fold sliding window: wl[8s+t] = bf16(W[(s+t)&4095]) so any
// 8-element circulant window starting at s is ONE aligned ds_read_b128 at
// byte 16s; consecutive lanes descend by 16B -> each 8-lane phase covers a
// contiguous 128B block (bank-conflict-free).
__global__ __launch_bounds__(512, 4)
void circ_mm(const float* __restrict__ X, const float* __restrict__ W,
             const float* __restrict__ bias, float* __restrict__ C) {
  extern __shared__ unsigned short smem[];
  unsigned short* __restrict__ wl = smem;            // 32768 bf16 = 64 KB
  unsigned short* __restrict__ al = smem + 8 * ND;   // dbuf 2 x [64][64] bf16 = 16 KB

  const int tid = threadIdx.x;
  const int bid = blockIdx.x;
  // XCD-aware mapping: XCD x serves m-panels {x, x+8}; 32 n-tiles share the
  // 1 MB X panel (+ wl) in that XCD's L2.
  const int x = bid & 7;
  const int i = bid >> 3;
  const int m0 = (x + ((i >> 5) << 3)) << 6;   // 0..960
  const int n0 = (i & 31) << 7;                // 0..3968

  // ---- build 8-fold sliding-window W: wl[e] = bf16(W[((e>>3)+(e&7)) & 4095]) ----
  for (int e4 = tid; e4 < 8192; e4 += 512) {
    const int m = e4 << 2;
    s4v u;
    #pragma unroll
    for (int j = 0; j < 4; ++j) {
      const int idx = (((m + j) >> 3) + ((m + j) & 7)) & NMASK;
      u[j] = (short)f2bf(W[idx]);
    }
    *(s4v*)(&wl[m]) = u;
  }

  // ---- A staging geometry: thread covers (srow, 8 consecutive k) ----
  const int srow = tid >> 3;        // 0..63
  const int seg = tid & 7;          // 16B segment within 128B row
  const float* gA = X + (m0 + srow) * ND + (seg << 3);
  const int woff = srow * 64 + ((seg << 3) ^ ((srow & 7) << 3));

  // ---- fragment geometry (mfma_f32_32x32x16_bf16) ----
  const int lane = tid & 63;
  const int lc = lane & 31;
  const int lh8 = (lane >> 5) << 3;
  const int wv = tid >> 6;          // 0..7
  const int wn = wv & 1;            // 64-col band within block
  const int kb = wv >> 1;           // K-quarter (16 k of each 64-k tile)

  int aoff[2];                      // [mf]
  #pragma unroll
  for (int mf = 0; mf < 2; ++mf) {
    const int row = mf * 32 + lc;
    aoff[mf] = row * 64 + (((kb << 4) + lh8) ^ ((row & 7) << 3));
  }

  int c0f[2];                       // (kb*16 + lh8 - col) & 4095, per n-fragment
  #pragma unroll
  for (int nf = 0; nf < 2; ++nf) {
    const int col = n0 + wn * 64 + nf * 32 + lc;
    c0f[nf] = ((kb << 4) + lh8 - col) & NMASK;
  }

  f16v acc[2][2];
  #pragma unroll
  for (int mf = 0; mf < 2; ++mf)
    #pragma unroll
    for (int nf = 0; nf < 2; ++nf)
      #pragma unroll
      for (int e = 0; e < 16; ++e) acc[mf][nf][e] = 0.f;

  // ---- prologue: stage A tile 0 ----
  {
    f4v g0 = *(const f4v*)(gA + 0);
    f4v g1 = *(const f4v*)(gA + 4);
    s8v u;
    #pragma unroll
    for (int j = 0; j < 4; ++j) {
      u[j] = (short)f2bf(g0[j]); u[4 + j] = (short)f2bf(g1[j]);
    }
    *(s8v*)(&al[woff]) = u;
  }
  __syncthreads();

  // ---- main K loop: 64 tiles of BK=64, one barrier per tile (T14 split) ----
  #pragma unroll 2
  for (int t = 0; t < 64; ++t) {
    const unsigned short* ab = al + (t & 1) * 4096;

    f4v g0, g1;
    if (t < 63) {                    // issue next-tile global loads first
      const float* gp = gA + (t + 1) * 64;
      g0 = *(const f4v*)(gp + 0);
      g1 = *(const f4v*)(gp + 4);
    }

    const s8v a0 = *(const s8v*)(&ab[aoff[0]]);
    const s8v a1 = *(const s8v*)(&ab[aoff[1]]);
    const int s0 = ((t << 6) + c0f[0]) & NMASK;
    const int s1 = ((t << 6) + c0f[1]) & NMASK;
    const s8v b0 = *(const s8v*)(&wl[s0 << 3]);
    const s8v b1 = *(const s8v*)(&wl[s1 << 3]);

    acc[0][0] = __builtin_amdgcn_mfma_f32_32x32x16_bf16(a0, b0, acc[0][0], 0, 0, 0);
    acc[1][0] = __builtin_amdgcn_mfma_f32_32x32x16_bf16(a1, b0, acc[1][0], 0, 0, 0);
    acc[0][1] = __builtin_amdgcn_mfma_f32_32x32x16_bf16(a0, b1, acc[0][1], 0, 0, 0);
    acc[1][1] = __builtin_amdgcn_mfma_f32_32x32x16_bf16(a1, b1, acc[1][1], 0, 0, 0);

    if (t < 63) {                    // convert + LDS-write after compute
      unsigned short* aw = al + ((t + 1) & 1) * 4096;
      s8v u;
      #pragma unroll
      for (int j = 0; j < 4; ++j) {
        u[j] = (short)f2bf(g0[j]); u[4 + j] = (short)f2bf(g1[j]);
      }
      *(s8v*)(&aw[woff]) = u;
    }
    __syncthreads();
  }

  // ---- epilogue: 4-way K reduction in LDS, then bias + store ----
  // C/D map: col=lane&31, row=(reg&3)+8*(reg>>2)+4*(lane>>5)
  const int lh4 = (lane >> 5) << 2;
  float* red = (float*)smem;        // 4 bands x [64][64] f32 = 64 KB (overlays wl)

  if (kb >= 2) {
    float* rb = red + (((wn << 1) + (kb - 2)) << 12);
    #pragma unroll
    for (int mf = 0; mf < 2; ++mf)
      #pragma unroll
      for (int nf = 0; nf < 2; ++nf)
        #pragma unroll
        for (int g = 0; g < 4; ++g)
          #pragma unroll
          for (int e = 0; e < 4; ++e)
            rb[(mf * 32 + g * 8 + lh4 + e) * 64 + nf * 32 + lc] = acc[mf][nf][g * 4 + e];
  }
  __syncthreads();
  if (kb < 2) {
    float* rb = red + (((wn << 1) + kb) << 12);
    #pragma unroll
    for (int mf = 0; mf < 2; ++mf)
      #pragma unroll
      for (int nf = 0; nf < 2; ++nf)
        #pragma unroll
        for (int g = 0; g < 4; ++g)
          #pragma unroll
          for (int e = 0; e < 4; ++e)
            acc[mf][nf][g * 4 + e] += rb[(mf * 32 + g * 8 + lh4 + e) * 64 + nf * 32 + lc];
  }
  __syncthreads();
  if (kb == 1) {
    float* rb = red + (wn << 12);
    #pragma unroll
    for (int mf = 0; mf < 2; ++mf)
      #pragma unroll
      for (int nf = 0; nf < 2; ++nf)
        #pragma unroll
        for (int g = 0; g < 4; ++g)
          #pragma unroll
          for (int e = 0; e < 4; ++e)
            rb[(mf * 32 + g * 8 + lh4 + e) * 64 + nf * 32 + lc] = acc[mf][nf][g * 4 + e];
  }
  __syncthreads();
  if (kb == 0) {
    float* rb = red + (wn << 12);
    #pragma unroll
    for (int nf = 0; nf < 2; ++nf) {
      const int col = n0 + wn * 64 + nf * 32 + lc;
      const float bv = bias[col];
      #pragma unroll
      for (int mf = 0; mf < 2; ++mf)
        #pragma unroll
        for (int g = 0; g < 4; ++g) {
          const int row = m0 + mf * 32 + g * 8 + lh4;
          #pragma unroll
          for (int e = 0; e < 4; ++e)
            C[(row + e) * ND + col] =
                acc[mf][nf][g * 4 + e] +
                rb[(mf * 32 + g * 8 + lh4 + e) * 64 + nf * 32 + lc] + bv;
        }
    }
  }
}

extern "C" void kernel_launch(void* const* d_in, const int* in_sizes, int n_in,
                              void* d_out, int out_size, void* d_ws, size_t ws_size,
                              hipStream_t stream) {
  (void)hipFuncSetAttribute((const void*)circ_mm,
                            hipFuncAttributeMaxDynamicSharedMemorySize, 81920);
  const float* X    = (const float*)d_in[0];
  const float* W    = (const float*)d_in[1];
  const float* bias = (const float*)d_in[2];
  circ_mm<<<dim3(512), dim3(512), 81920, stream>>>(X, W, bias, (float*)d_out);
}

// Round 3
// 50.337 us; speedup vs baseline: 1.2544x; 1.0441x over previous
//
#include <hip/hip_runtime.h>

typedef short s4v __attribute__((ext_vector_type(4)));
typedef short s8v __attribute__((ext_vector_type(8)));
typedef float f4v __attribute__((ext_vector_type(4)));
typedef float f16v __attribute__((ext_vector_type(16)));

#define ND 4096
#define NMASK 4095

__device__ __forceinline__ unsigned short f2bf(float f) {
  __bf16 h = (__bf16)f;
  return __builtin_bit_cast(unsigned short, h);
}

// BM=64, BN=128, BK=64. 512 threads = 8 waves: wn = wv&1 (64-col band),
// kb = wv>>1 (K-quarter). Each wave: 64 rows x its 64 cols (2x2 frags of
// 32x32x16) over a quarter of K; positional cross-wave LDS reduction at end.
// wl: 8-fold sliding window wl[8s+t] = bf16(W[(s+t)&4095]) -> any 8-elem
// circulant window = ONE aligned ds_read_b128 at byte 16s (conflict-free).
// Depth-2 global prefetch: tile t issues loads for t+2, writes t+1 to LDS
// (~1.75 tile-times in flight -> vmcnt stall off the per-tile critical path).
__global__ __launch_bounds__(512, 4)
void circ_mm(const float* __restrict__ X, const float* __restrict__ W,
             const float* __restrict__ bias, float* __restrict__ C) {
  extern __shared__ unsigned short smem[];
  unsigned short* __restrict__ wl = smem;            // 32768 bf16 = 64 KB
  unsigned short* __restrict__ al = smem + 8 * ND;   // dbuf 2 x [64][64] bf16 = 16 KB

  const int tid = threadIdx.x;
  const int bid = blockIdx.x;
  // XCD-aware mapping: XCD x serves m-panels {x, x+8}; 32 n-tiles share the
  // 2 MB X panel in that XCD's L2.
  const int x = bid & 7;
  const int i = bid >> 3;
  const int m0 = (x + ((i >> 5) << 3)) << 6;   // 0..960
  const int n0 = (i & 31) << 7;                // 0..3968

  // ---- build 8-fold sliding-window W ----
  for (int e4 = tid; e4 < 8192; e4 += 512) {
    const int m = e4 << 2;
    s4v u;
    #pragma unroll
    for (int j = 0; j < 4; ++j) {
      const int idx = (((m + j) >> 3) + ((m + j) & 7)) & NMASK;
      u[j] = (short)f2bf(W[idx]);
    }
    *(s4v*)(&wl[m]) = u;
  }

  // ---- A staging geometry: thread covers (srow, 8 consecutive k) ----
  const int srow = tid >> 3;        // 0..63
  const int seg = tid & 7;          // 16B segment within 128B row
  const float* gA = X + (m0 + srow) * ND + (seg << 3);
  const int woff = srow * 64 + ((seg << 3) ^ ((srow & 7) << 3));

  // ---- fragment geometry (mfma_f32_32x32x16_bf16) ----
  const int lane = tid & 63;
  const int lc = lane & 31;
  const int lh8 = (lane >> 5) << 3;
  const int wv = tid >> 6;          // 0..7
  const int wn = wv & 1;            // 64-col band within block
  const int kb = wv >> 1;           // K-quarter (16 k of each 64-k tile)

  int aoff[2];
  #pragma unroll
  for (int mf = 0; mf < 2; ++mf) {
    const int row = mf * 32 + lc;
    aoff[mf] = row * 64 + (((kb << 4) + lh8) ^ ((row & 7) << 3));
  }

  int c0f[2];                       // (kb*16 + lh8 - col) & 4095
  #pragma unroll
  for (int nf = 0; nf < 2; ++nf) {
    const int col = n0 + wn * 64 + nf * 32 + lc;
    c0f[nf] = ((kb << 4) + lh8 - col) & NMASK;
  }

  f16v acc[2][2];
  #pragma unroll
  for (int mf = 0; mf < 2; ++mf)
    #pragma unroll
    for (int nf = 0; nf < 2; ++nf)
      #pragma unroll
      for (int e = 0; e < 16; ++e) acc[mf][nf][e] = 0.f;

  // ---- prologue: load tiles 0 and 1; stage tile 0 ----
  f4v Ga0, Ga1, Gb0, Gb1;
  Ga0 = *(const f4v*)(gA + 0);
  Ga1 = *(const f4v*)(gA + 4);
  Gb0 = *(const f4v*)(gA + 64);
  Gb1 = *(const f4v*)(gA + 68);
  {
    s8v u;
    #pragma unroll
    for (int j = 0; j < 4; ++j) {
      u[j] = (short)f2bf(Ga0[j]); u[4 + j] = (short)f2bf(Ga1[j]);
    }
    *(s8v*)(&al[woff]) = u;
  }
  __syncthreads();

  // ---- main K loop: explicit 2x unroll, named prefetch buffers ----
  for (int t = 0; t < 64; t += 2) {
    // ===== even tile t: compute al[0]; write tile t+1 from Gb; load t+2 -> Ga
    if (t + 2 < 64) {
      const float* gp = gA + (t + 2) * 64;
      Ga0 = *(const f4v*)(gp + 0);
      Ga1 = *(const f4v*)(gp + 4);
    }
    {
      const unsigned short* ab = al;
      const s8v a0 = *(const s8v*)(&ab[aoff[0]]);
      const s8v a1 = *(const s8v*)(&ab[aoff[1]]);
      const int s0 = ((t << 6) + c0f[0]) & NMASK;
      const int s1 = ((t << 6) + c0f[1]) & NMASK;
      const s8v b0 = *(const s8v*)(&wl[s0 << 3]);
      const s8v b1 = *(const s8v*)(&wl[s1 << 3]);
      acc[0][0] = __builtin_amdgcn_mfma_f32_32x32x16_bf16(a0, b0, acc[0][0], 0, 0, 0);
      acc[1][0] = __builtin_amdgcn_mfma_f32_32x32x16_bf16(a1, b0, acc[1][0], 0, 0, 0);
      acc[0][1] = __builtin_amdgcn_mfma_f32_32x32x16_bf16(a0, b1, acc[0][1], 0, 0, 0);
      acc[1][1] = __builtin_amdgcn_mfma_f32_32x32x16_bf16(a1, b1, acc[1][1], 0, 0, 0);
    }
    {  // write tile t+1 (t+1 <= 63 always here)
      unsigned short* aw = al + 4096;
      s8v u;
      #pragma unroll
      for (int j = 0; j < 4; ++j) {
        u[j] = (short)f2bf(Gb0[j]); u[4 + j] = (short)f2bf(Gb1[j]);
      }
      *(s8v*)(&aw[woff]) = u;
    }
    __syncthreads();

    // ===== odd tile t+1: compute al[1]; write tile t+2 from Ga; load t+3 -> Gb
    if (t + 3 < 64) {
      const float* gp = gA + (t + 3) * 64;
      Gb0 = *(const f4v*)(gp + 0);
      Gb1 = *(const f4v*)(gp + 4);
    }
    {
      const unsigned short* ab = al + 4096;
      const s8v a0 = *(const s8v*)(&ab[aoff[0]]);
      const s8v a1 = *(const s8v*)(&ab[aoff[1]]);
      const int s0 = (((t + 1) << 6) + c0f[0]) & NMASK;
      const int s1 = (((t + 1) << 6) + c0f[1]) & NMASK;
      const s8v b0 = *(const s8v*)(&wl[s0 << 3]);
      const s8v b1 = *(const s8v*)(&wl[s1 << 3]);
      acc[0][0] = __builtin_amdgcn_mfma_f32_32x32x16_bf16(a0, b0, acc[0][0], 0, 0, 0);
      acc[1][0] = __builtin_amdgcn_mfma_f32_32x32x16_bf16(a1, b0, acc[1][0], 0, 0, 0);
      acc[0][1] = __builtin_amdgcn_mfma_f32_32x32x16_bf16(a0, b1, acc[0][1], 0, 0, 0);
      acc[1][1] = __builtin_amdgcn_mfma_f32_32x32x16_bf16(a1, b1, acc[1][1], 0, 0, 0);
    }
    if (t + 2 < 64) {  // write tile t+2
      unsigned short* aw = al;
      s8v u;
      #pragma unroll
      for (int j = 0; j < 4; ++j) {
        u[j] = (short)f2bf(Ga0[j]); u[4 + j] = (short)f2bf(Ga1[j]);
      }
      *(s8v*)(&aw[woff]) = u;
    }
    __syncthreads();
  }

  // ---- epilogue: positional 4-way K reduction (b128), then bias + store ----
  // Lane l of (wn,kb) holds the same (row,col) set as lane l of (wn,kb');
  // exchange the 64 acc floats positionally: chunk j at red[band][(j*64+l)*4].
  float* red = (float*)smem;        // 4 bands x 16 KB = 64 KB (overlays wl)
  float* rb;

  // round 1: kb2 -> band wn, kb3 -> band 2+wn
  if (kb >= 2) {
    rb = red + ((kb - 2) * 2 + wn) * 4096;
    #pragma unroll
    for (int mf = 0; mf < 2; ++mf)
      #pragma unroll
      for (int nf = 0; nf < 2; ++nf)
        #pragma unroll
        for (int q = 0; q < 4; ++q) {
          const int j = ((mf * 2 + nf) * 4 + q);
          f4v v;
          #pragma unroll
          for (int e = 0; e < 4; ++e) v[e] = acc[mf][nf][q * 4 + e];
          *(f4v*)(&rb[(j * 64 + lane) * 4]) = v;
        }
  }
  __syncthreads();
  if (kb < 2) {
    rb = red + (kb * 2 + wn) * 4096;
    #pragma unroll
    for (int mf = 0; mf < 2; ++mf)
      #pragma unroll
      for (int nf = 0; nf < 2; ++nf)
        #pragma unroll
        for (int q = 0; q < 4; ++q) {
          const int j = ((mf * 2 + nf) * 4 + q);
          const f4v v = *(const f4v*)(&rb[(j * 64 + lane) * 4]);
          #pragma unroll
          for (int e = 0; e < 4; ++e) acc[mf][nf][q * 4 + e] += v[e];
        }
  }
  __syncthreads();
  // round 2: kb1 -> band wn
  if (kb == 1) {
    rb = red + wn * 4096;
    #pragma unroll
    for (int mf = 0; mf < 2; ++mf)
      #pragma unroll
      for (int nf = 0; nf < 2; ++nf)
        #pragma unroll
        for (int q = 0; q < 4; ++q) {
          const int j = ((mf * 2 + nf) * 4 + q);
          f4v v;
          #pragma unroll
          for (int e = 0; e < 4; ++e) v[e] = acc[mf][nf][q * 4 + e];
          *(f4v*)(&rb[(j * 64 + lane) * 4]) = v;
        }
  }
  __syncthreads();
  if (kb == 0) {
    rb = red + wn * 4096;
    #pragma unroll
    for (int mf = 0; mf < 2; ++mf)
      #pragma unroll
      for (int nf = 0; nf < 2; ++nf)
        #pragma unroll
        for (int q = 0; q < 4; ++q) {
          const int j = ((mf * 2 + nf) * 4 + q);
          const f4v v = *(const f4v*)(&rb[(j * 64 + lane) * 4]);
          #pragma unroll
          for (int e = 0; e < 4; ++e) acc[mf][nf][q * 4 + e] += v[e];
        }
    const int lh4 = (lane >> 5) << 2;
    #pragma unroll
    for (int nf = 0; nf < 2; ++nf) {
      const int col = n0 + wn * 64 + nf * 32 + lc;
      const float bv = bias[col];
      #pragma unroll
      for (int mf = 0; mf < 2; ++mf)
        #pragma unroll
        for (int g = 0; g < 4; ++g) {
          const int row = m0 + mf * 32 + g * 8 + lh4;
          #pragma unroll
          for (int e = 0; e < 4; ++e)
            C[(row + e) * ND + col] = acc[mf][nf][g * 4 + e] + bv;
        }
    }
  }
}

extern "C" void kernel_launch(void* const* d_in, const int* in_sizes, int n_in,
                              void* d_out, int out_size, void* d_ws, size_t ws_size,
                              hipStream_t stream) {
  (void)hipFuncSetAttribute((const void*)circ_mm,
                            hipFuncAttributeMaxDynamicSharedMemorySize, 81920);
  const float* X    = (const float*)d_in[0];
  const float* W    = (const float*)d_in[1];
  const float* bias = (const float*)d_in[2];
  circ_mm<<<dim3(512), dim3(512), 81920, stream>>>(X, W, bias, (float*)d_out);
}